// Round 9
// baseline (32114.871 us; speedup 1.0000x reference)
//
#include <hip/hip_runtime.h>
#include <math.h>

// ---------------- problem constants ----------------
constexpr int MM = 8;      // batch of GPs
constexpr int NC = 1024;   // context points
constexpr int NT = 512;    // target points

// Workspace (floats):
//  Kb   : MM*1024*1024   (K raw/Schur -> G = K^-1 after syrk)
//  Ab   : MM*1024*1024   (128-grain L panels + diag-block inverses -> A = L^-1)
//  Tb   : MM*512*512     (trinv temp; S1/S2 accumulators at predict)
//  Ktc  : MM*NT*NC
//  alpha: MM*1024
//  scal : MM*32  ([0..3] raw, [4..7] adam m, [8..11] adam v, [12]ls [13]os [14]noi [15]cm)
//  acc  : MM*8   ([T1, T2, trG] per m)
//  ctr  : MM u32 (reduce completion tickets)
constexpr size_t OFF_A     = (size_t)MM * 1024 * 1024;
constexpr size_t OFF_T     = OFF_A * 2;
constexpr size_t OFF_KTC   = OFF_T + (size_t)MM * 512 * 512;
constexpr size_t OFF_ALPHA = OFF_KTC + (size_t)MM * NT * NC;
constexpr size_t OFF_SCAL  = OFF_ALPHA + (size_t)MM * 1024;
constexpr size_t OFF_ACC   = OFF_SCAL + (size_t)MM * 32;
constexpr size_t OFF_CTR   = OFF_ACC + (size_t)MM * 8;

#define S5 2.2360679775f

__device__ __forceinline__ float sigmf(float x) { return 1.0f / (1.0f + expf(-x)); }
__device__ __forceinline__ float softplusf(float x) { return fmaxf(x, 0.0f) + log1pf(expf(-fabsf(x))); }

__device__ __forceinline__ void lt_decode(int x, int& i, int& j) {
  int ii = 0;
  while ((ii + 1) * (ii + 2) / 2 <= x) ++ii;
  i = ii; j = x - ii * (ii + 1) / 2;
}

// 64-grain shared struct (predW, reduce) — identical to r8
struct SMem {
  float Ls[64 * 65];
  float Us[64 * 65];
  float Tt[32 * 33];
  float dvec[64];
  float As[16][68];
  float Bs[16][68];
  float xi[64][3];
  float xj[64][3];
  float ai[64];
  float aj[64];
  float red[4][4];
};

// 128-grain GEMM shared struct (~18 KB)
struct SMem128 {
  float As[16][132];
  float Bs[16][132];
  float ai[128];
  float aj[128];
  float red[4][4];
};

// factor128 staging buffers (~55 KB)
struct FactBuf {
  float Ls[64 * 65];
  float Us[64 * 65];
  float P[64 * 65];
  float Tt[32 * 33];
  float dvec[64];
};

// ---------------- 64-tile GEMM (4x4 micro, register prefetch) ----------------
template <int TA, int TB>
__device__ __forceinline__ void gemm64(const float* __restrict__ A, int lda,
                                       const float* __restrict__ B, int ldb,
                                       int kBeg, int kEnd, float acc[4][4], SMem& sm) {
  int tid = threadIdx.x, tx = tid & 15, ty = tid >> 4;
  float ra[4], rb[4];
  auto ldAB = [&](int k0) {
#pragma unroll
    for (int q = 0; q < 4; ++q) {
      int e = tid + (q << 8);
      if (TA) { int kk = e >> 6, r = e & 63; ra[q] = A[(size_t)(k0 + kk) * lda + r]; }
      else    { int r = e >> 4, kk = e & 15; ra[q] = A[(size_t)r * lda + k0 + kk]; }
      if (TB) { int c = e >> 4, kk = e & 15; rb[q] = B[(size_t)c * ldb + k0 + kk]; }
      else    { int kk = e >> 6, c = e & 63; rb[q] = B[(size_t)(k0 + kk) * ldb + c]; }
    }
  };
  ldAB(kBeg);
  for (int k0 = kBeg; k0 < kEnd; k0 += 16) {
    __syncthreads();
#pragma unroll
    for (int q = 0; q < 4; ++q) {
      int e = tid + (q << 8);
      if (TA) sm.As[e >> 6][e & 63] = ra[q]; else sm.As[e & 15][e >> 4] = ra[q];
      if (TB) sm.Bs[e & 15][e >> 4] = rb[q]; else sm.Bs[e >> 6][e & 63] = rb[q];
    }
    __syncthreads();
    if (k0 + 16 < kEnd) ldAB(k0 + 16);
#pragma unroll
    for (int kk = 0; kk < 16; ++kk) {
      float a[4], b[4];
#pragma unroll
      for (int i = 0; i < 4; ++i) a[i] = sm.As[kk][ty * 4 + i];
#pragma unroll
      for (int j = 0; j < 4; ++j) b[j] = sm.Bs[kk][tx * 4 + j];
#pragma unroll
      for (int i = 0; i < 4; ++i)
#pragma unroll
        for (int j = 0; j < 4; ++j) acc[i][j] = fmaf(a[i], b[j], acc[i][j]);
    }
  }
}

// ---------------- 128-tile GEMM (8x8 micro, register prefetch) ---------------
template <int TA, int TB>
__device__ __forceinline__ void gemm128(const float* __restrict__ A, int lda,
                                        const float* __restrict__ B, int ldb,
                                        int kBeg, int kEnd, float acc[8][8], SMem128& sm) {
  int tid = threadIdx.x, tx = tid & 15, ty = tid >> 4;
  float ra[8], rb[8];
  auto ldAB = [&](int k0) {
#pragma unroll
    for (int q = 0; q < 8; ++q) {
      int e = tid + (q << 8);
      if (TA) { int kk = e >> 7, r = e & 127; ra[q] = A[(size_t)(k0 + kk) * lda + r]; }
      else    { int r = e >> 4, kk = e & 15;  ra[q] = A[(size_t)r * lda + k0 + kk]; }
      if (TB) { int c = e >> 4, kk = e & 15;  rb[q] = B[(size_t)c * ldb + k0 + kk]; }
      else    { int kk = e >> 7, c = e & 127; rb[q] = B[(size_t)(k0 + kk) * ldb + c]; }
    }
  };
  ldAB(kBeg);
  for (int k0 = kBeg; k0 < kEnd; k0 += 16) {
    __syncthreads();
#pragma unroll
    for (int q = 0; q < 8; ++q) {
      int e = tid + (q << 8);
      if (TA) sm.As[e >> 7][e & 127] = ra[q]; else sm.As[e & 15][e >> 4] = ra[q];
      if (TB) sm.Bs[e & 15][e >> 4] = rb[q];  else sm.Bs[e >> 7][e & 127] = rb[q];
    }
    __syncthreads();
    if (k0 + 16 < kEnd) ldAB(k0 + 16);
#pragma unroll
    for (int kk = 0; kk < 16; ++kk) {
      float a[8], b[8];
#pragma unroll
      for (int i = 0; i < 8; ++i) a[i] = sm.As[kk][ty * 8 + i];
#pragma unroll
      for (int j = 0; j < 8; ++j) b[j] = sm.Bs[kk][tx * 8 + j];
#pragma unroll
      for (int i = 0; i < 8; ++i)
#pragma unroll
        for (int j = 0; j < 8; ++j) acc[i][j] = fmaf(a[i], b[j], acc[i][j]);
    }
  }
}

// ---------------- in-LDS 64x64 SPD factor + triangular inverse (ptr-based) ---
__device__ void f64_inlds(float* Ls, float* Us, float* Tt, float* dvec,
                          float* Uout, int ldu) {
  int tid = threadIdx.x;
  int tx = tid & 15, ty = tid >> 4;
  for (int j = 0; j < 63; ++j) {
    float rinv = 1.0f / Ls[j * 65 + j];
    for (int i = j + 1 + ty; i < 64; i += 16) {
      float lij = Ls[i * 65 + j] * rinv;
      for (int c = j + 1 + tx; c <= i; c += 16) Ls[i * 65 + c] -= lij * Ls[c * 65 + j];
    }
    __syncthreads();
  }
  if (tid < 64) dvec[tid] = 1.0f / sqrtf(Ls[tid * 65 + tid]);
  __syncthreads();
  for (int e = tid; e < 4096; e += 256) { int r = e >> 6, c = e & 63; if (c <= r) Ls[r * 65 + c] *= dvec[c]; }
  __syncthreads();
  for (int e = tid; e < 64 * 65; e += 256) Us[e] = 0.0f;
  __syncthreads();
  if (tid < 64) {
    int b = tid >> 5, c0 = tid & 31, base = b * 32, gc = base + c0;
    Us[gc * 65 + gc] = 1.0f / Ls[gc * 65 + gc];
    for (int r = c0 + 1; r < 32; ++r) {
      int gr = base + r;
      float acc = 0.0f;
      for (int l = c0; l < r; ++l) acc += Ls[gr * 65 + base + l] * Us[(base + l) * 65 + gc];
      Us[gr * 65 + gc] = -acc / Ls[gr * 65 + gr];
    }
  }
  __syncthreads();
  for (int e = tid; e < 1024; e += 256) {
    int r = e >> 5, c = e & 31;
    float acc = 0.0f;
    for (int l = c; l < 32; ++l) acc += Ls[(32 + r) * 65 + l] * Us[l * 65 + c];
    Tt[r * 33 + c] = acc;
  }
  __syncthreads();
  for (int e = tid; e < 1024; e += 256) {
    int r = e >> 5, c = e & 31;
    float acc = 0.0f;
    for (int l = 0; l <= r; ++l) acc += Us[(32 + r) * 65 + 32 + l] * Tt[l * 33 + c];
    Us[(32 + r) * 65 + c] = -acc;
  }
  __syncthreads();
  for (int e = tid; e < 4096; e += 256) { int r = e >> 6, c = e & 63; Uout[(size_t)r * ldu + c] = Us[r * 65 + c]; }
}

// ---------------- staged 128x128 SPD factor + inverse (one block) ------------
// Reads the raw SPD 128-tile at Km[r0,r0], writes full 128x128 Linv (zeros
// above diag) into Am[r0,r0].
__device__ void factor128dev(FactBuf& fb, float* Km, float* Am, int r0, int n) {
  int tid = threadIdx.x, tx = tid & 15, ty = tid >> 4;
  // S1: K11 -> Ls; factor -> U11 (global + fb.Us)
  for (int e = tid; e < 4096; e += 256) { int r = e >> 6, c = e & 63; fb.Ls[r * 65 + c] = Km[(size_t)(r0 + r) * n + r0 + c]; }
  __syncthreads();
  f64_inlds(fb.Ls, fb.Us, fb.Tt, fb.dvec, Am + (size_t)r0 * n + r0, n);
  // S2: P(L21) = A21 * U11^T  (A21 loaded into P, overwritten via registers)
  for (int e = tid; e < 4096; e += 256) { int r = e >> 6, c = e & 63; fb.P[r * 65 + c] = Km[(size_t)(r0 + 64 + r) * n + r0 + c]; }
  __syncthreads();
  {
    float res[4][4] = {};
    for (int l = 0; l < 64; ++l) {
      float a[4], b[4];
#pragma unroll
      for (int ii = 0; ii < 4; ++ii) a[ii] = fb.P[(ty * 4 + ii) * 65 + l];
#pragma unroll
      for (int jj = 0; jj < 4; ++jj) b[jj] = fb.Us[(tx * 4 + jj) * 65 + l];
#pragma unroll
      for (int ii = 0; ii < 4; ++ii)
#pragma unroll
        for (int jj = 0; jj < 4; ++jj) res[ii][jj] = fmaf(a[ii], b[jj], res[ii][jj]);
    }
    __syncthreads();
#pragma unroll
    for (int ii = 0; ii < 4; ++ii)
#pragma unroll
      for (int jj = 0; jj < 4; ++jj) fb.P[(ty * 4 + ii) * 65 + tx * 4 + jj] = res[ii][jj];
  }
  __syncthreads();
  // S3: Ls = A22 - P P^T
  for (int e = tid; e < 4096; e += 256) { int r = e >> 6, c = e & 63; fb.Ls[r * 65 + c] = Km[(size_t)(r0 + 64 + r) * n + r0 + 64 + c]; }
  __syncthreads();
  {
    float acc[4][4] = {};
    for (int l = 0; l < 64; ++l) {
      float a[4], b[4];
#pragma unroll
      for (int ii = 0; ii < 4; ++ii) a[ii] = fb.P[(ty * 4 + ii) * 65 + l];
#pragma unroll
      for (int jj = 0; jj < 4; ++jj) b[jj] = fb.P[(tx * 4 + jj) * 65 + l];
#pragma unroll
      for (int ii = 0; ii < 4; ++ii)
#pragma unroll
        for (int jj = 0; jj < 4; ++jj) acc[ii][jj] = fmaf(a[ii], b[jj], acc[ii][jj]);
    }
#pragma unroll
    for (int ii = 0; ii < 4; ++ii)
#pragma unroll
      for (int jj = 0; jj < 4; ++jj) fb.Ls[(ty * 4 + ii) * 65 + tx * 4 + jj] -= acc[ii][jj];
  }
  __syncthreads();
  // S4: factor A22' -> U22 (global + fb.Us)
  f64_inlds(fb.Ls, fb.Us, fb.Tt, fb.dvec, Am + (size_t)(r0 + 64) * n + r0 + 64, n);
  // S5: reload U11 -> Ls; T = P * U11 (into P)
  for (int e = tid; e < 4096; e += 256) { int r = e >> 6, c = e & 63; fb.Ls[r * 65 + c] = Am[(size_t)(r0 + r) * n + r0 + c]; }
  __syncthreads();
  {
    float res[4][4] = {};
    for (int l = 0; l < 64; ++l) {
      float a[4], b[4];
#pragma unroll
      for (int ii = 0; ii < 4; ++ii) a[ii] = fb.P[(ty * 4 + ii) * 65 + l];
#pragma unroll
      for (int jj = 0; jj < 4; ++jj) b[jj] = fb.Ls[l * 65 + tx * 4 + jj];
#pragma unroll
      for (int ii = 0; ii < 4; ++ii)
#pragma unroll
        for (int jj = 0; jj < 4; ++jj) res[ii][jj] = fmaf(a[ii], b[jj], res[ii][jj]);
    }
    __syncthreads();
#pragma unroll
    for (int ii = 0; ii < 4; ++ii)
#pragma unroll
      for (int jj = 0; jj < 4; ++jj) fb.P[(ty * 4 + ii) * 65 + tx * 4 + jj] = res[ii][jj];
  }
  __syncthreads();
  // S6: U21 = -U22 * T -> global; zero upper-right subtile
  {
    float res[4][4] = {};
    for (int l = 0; l < 64; ++l) {
      float a[4], b[4];
#pragma unroll
      for (int ii = 0; ii < 4; ++ii) a[ii] = fb.Us[(ty * 4 + ii) * 65 + l];
#pragma unroll
      for (int jj = 0; jj < 4; ++jj) b[jj] = fb.P[l * 65 + tx * 4 + jj];
#pragma unroll
      for (int ii = 0; ii < 4; ++ii)
#pragma unroll
        for (int jj = 0; jj < 4; ++jj) res[ii][jj] = fmaf(a[ii], b[jj], res[ii][jj]);
    }
#pragma unroll
    for (int ii = 0; ii < 4; ++ii)
#pragma unroll
      for (int jj = 0; jj < 4; ++jj)
        Am[(size_t)(r0 + 64 + ty * 4 + ii) * n + r0 + tx * 4 + jj] = -res[ii][jj];
  }
  for (int e = tid; e < 4096; e += 256) { int r = e >> 6, c = e & 63; Am[(size_t)(r0 + r) * n + r0 + 64 + c] = 0.0f; }
}

// ---------------- kernels (job = blockIdx.x, m = blockIdx.y) -----------------

__global__ __launch_bounds__(256) void k_init(float* ws) {
  int t = threadIdx.x;
  float* scal = ws + OFF_SCAL;
  float* acc = ws + OFF_ACC;
  if (t < MM) {
    float* s = scal + t * 32;
    for (int i = 0; i < 12; ++i) s[i] = 0.0f;
    float sp0 = 0.69314718056f;
    s[12] = sp0; s[13] = sp0; s[14] = sp0 + 1e-4f; s[15] = 0.0f;
  }
  if (t < MM * 8) acc[t] = 0.0f;
  if (t < MM) ((unsigned*)(ws + OFF_CTR))[t] = 0u;
}

// build K lower 64-tiles; side tasks: jobs 1..4 zero alpha, job 5 zeroes acc+ticket
__global__ __launch_bounds__(256) void k_buildK(const float* __restrict__ xc, float* ws, int n) {
  __shared__ float xi[64][3], xj[64][3];
  int job = blockIdx.x, m = blockIdx.y, tid = threadIdx.x;
  const float* xm = xc + (size_t)m * NC * 3;
  float* Km = ws + (size_t)m * 1048576;
  const float* sT = ws + OFF_SCAL + m * 32;
  float ls = sT[12], os = sT[13], noi = sT[14];
  float il2 = 1.0f / (ls * ls);
  if (job >= 1 && job <= 4) {
    int zi = (job - 1) * 256 + tid;
    if (zi < n) ws[OFF_ALPHA + (size_t)m * 1024 + zi] = 0.0f;
  }
  if (job == 5) {
    if (tid < 4) ws[OFF_ACC + m * 8 + tid] = 0.0f;
    if (tid == 4) ((unsigned*)(ws + OFF_CTR))[m] = 0u;
  }
  int bi, bj; lt_decode(job, bi, bj);
  if (tid < 64) {
    int r = bi * 64 + tid;
    xi[tid][0] = xm[r * 3 + 0]; xi[tid][1] = xm[r * 3 + 1]; xi[tid][2] = xm[r * 3 + 2];
  } else if (tid < 128) {
    int lr = tid - 64; int r = bj * 64 + lr;
    xj[lr][0] = xm[r * 3 + 0]; xj[lr][1] = xm[r * 3 + 1]; xj[lr][2] = xm[r * 3 + 2];
  }
  __syncthreads();
  for (int e = tid; e < 4096; e += 256) {
    int r = e >> 6, c = e & 63;
    float d0 = xi[r][0] - xj[c][0], d1 = xi[r][1] - xj[c][1], d2 = xi[r][2] - xj[c][2];
    float r2 = d0 * d0 + d1 * d1 + d2 * d2;
    float z = fmaxf(r2 * il2, 1e-12f);
    float dd = sqrtf(z);
    float kv = os * (1.0f + S5 * dd + (5.0f / 3.0f) * z) * __expf(-S5 * dd);
    if (bi == bj && r == c) kv += noi;
    Km[(size_t)(bi * 64 + r) * n + bj * 64 + c] = kv;
  }
}

// standalone factor of diag 128-tile kk (used for kk=0)
__global__ __launch_bounds__(256) void k_factor128(float* ws, int kk, int n) {
  __shared__ FactBuf fb;
  int m = blockIdx.x;
  factor128dev(fb, ws + (size_t)m * 1048576, ws + OFF_A + (size_t)m * 1048576, kk * 128, n);
}

// panel: P_i = K[i,k] * Linv128^T -> stored in Ab (these are L's 128-tiles)
__global__ __launch_bounds__(256) void k_panel128(float* ws, int k, int n) {
  __shared__ SMem128 sm;
  int m = blockIdx.y, i = k + 1 + blockIdx.x;
  int tx = threadIdx.x & 15, ty = threadIdx.x >> 4;
  float* Km = ws + (size_t)m * 1048576;
  float* Am = ws + OFF_A + (size_t)m * 1048576;
  float acc[8][8] = {};
  gemm128<0, 1>(Km + (size_t)(i * 128) * n + k * 128, n,
                Am + (size_t)(k * 128) * n + k * 128, n, 0, 128, acc, sm);
  float* P = Am + (size_t)(i * 128) * n + k * 128;
#pragma unroll
  for (int ii = 0; ii < 8; ++ii)
#pragma unroll
    for (int jj = 0; jj < 8; ++jj) P[(size_t)(ty * 8 + ii) * n + tx * 8 + jj] = acc[ii][jj];
}

// trail: K[i,j] -= P_i P_j^T (panels from Ab). Job 0 = tile (k+1,k+1):
// writes its update then factors+inverts that tile in-block (fused diag).
__global__ __launch_bounds__(256) void k_trailF128(float* ws, int k, int n) {
  __shared__ union { SMem128 g; FactBuf f; } sm;
  int job = blockIdx.x, m = blockIdx.y;
  int tx = threadIdx.x & 15, ty = threadIdx.x >> 4;
  float* Km = ws + (size_t)m * 1048576;
  float* Am = ws + OFF_A + (size_t)m * 1048576;
  int di, dj; lt_decode(job, di, dj);
  int i = k + 1 + di, j = k + 1 + dj;
  float acc[8][8] = {};
  gemm128<0, 1>(Am + (size_t)(i * 128) * n + k * 128, n,
                Am + (size_t)(j * 128) * n + k * 128, n, 0, 128, acc, sm.g);
  float* C = Km + (size_t)(i * 128) * n + j * 128;
#pragma unroll
  for (int ii = 0; ii < 8; ++ii)
#pragma unroll
    for (int jj = 0; jj < 8; ++jj)
      C[(size_t)(ty * 8 + ii) * n + tx * 8 + jj] -= acc[ii][jj];
  if (job == 0) {
    __syncthreads();  // drain gemm LDS reads + global writes before union reuse
    factor128dev(sm.f, Km, Am, (k + 1) * 128, n);
  }
}

// trinv levels at 128-grain tiles (block-lower doubling; panels+invs in Ab)
__global__ __launch_bounds__(256) void k_trinvT(float* ws, int s, int n) {
  __shared__ SMem128 sm;
  int job = blockIdx.x, m = blockIdx.y;
  int tx = threadIdx.x & 15, ty = threadIdx.x >> 4;
  float* Am = ws + OFF_A + (size_t)m * 1048576;
  float* Tm = ws + OFF_T + (size_t)m * 262144;
  int st = s >> 7;
  int p = job / (st * st), rem = job % (st * st);
  int ti = rem / st, tj = rem % st;
  int base = p * 2 * s;
  float acc[8][8] = {};
  gemm128<0, 0>(Am + (size_t)(base + s + ti * 128) * n + base, n,
                Am + (size_t)base * n + base + tj * 128, n, tj * 128, s, acc, sm);
  float* C = Tm + (size_t)p * s * s + (size_t)(ti * 128) * s + tj * 128;
#pragma unroll
  for (int ii = 0; ii < 8; ++ii)
#pragma unroll
    for (int jj = 0; jj < 8; ++jj) C[(size_t)(ty * 8 + ii) * s + tx * 8 + jj] = acc[ii][jj];
}

__global__ __launch_bounds__(256) void k_trinvA(float* ws, int s, int n) {
  __shared__ SMem128 sm;
  int job = blockIdx.x, m = blockIdx.y;
  int tx = threadIdx.x & 15, ty = threadIdx.x >> 4;
  float* Am = ws + OFF_A + (size_t)m * 1048576;
  const float* Tm = ws + OFF_T + (size_t)m * 262144;
  int st = s >> 7;
  int p = job / (st * st), rem = job % (st * st);
  int ti = rem / st, tj = rem % st;
  int base = p * 2 * s;
  float acc[8][8] = {};
  gemm128<0, 0>(Am + (size_t)(base + s + ti * 128) * n + base + s, n,
                Tm + (size_t)p * s * s + tj * 128, s, 0, (ti + 1) * 128, acc, sm);
  float* C = Am + (size_t)(base + s + ti * 128) * n + base + tj * 128;
#pragma unroll
  for (int ii = 0; ii < 8; ++ii)
#pragma unroll
    for (int jj = 0; jj < 8; ++jj) C[(size_t)(ty * 8 + ii) * n + tx * 8 + jj] = -acc[ii][jj];
}

// syrk (128-tile) + fused alpha (+= G*(y-c)) + fused tr(G)
__global__ __launch_bounds__(256) void k_syrkAT(const float* __restrict__ yc, float* ws, int n) {
  __shared__ SMem128 sm;
  int job = blockIdx.x, m = blockIdx.y, tid = threadIdx.x;
  int tx = tid & 15, ty = tid >> 4;
  const float* Am = ws + OFF_A + (size_t)m * 1048576;
  float* Gm = ws + (size_t)m * 1048576;
  const float* ym = yc + (size_t)m * NC;
  float* accp = ws + OFF_ACC + m * 8;
  float* al = ws + OFF_ALPHA + (size_t)m * 1024;
  float cm = ws[OFF_SCAL + m * 32 + 15];
  int ib, jb; lt_decode(job, ib, jb);
  if (tid < 128) sm.ai[tid] = ym[ib * 128 + tid] - cm;
  else sm.aj[tid - 128] = ym[jb * 128 + tid - 128] - cm;
  float acc[8][8] = {};
  gemm128<1, 0>(Am + ib * 128, n, Am + jb * 128, n, ib * 128, n, acc, sm);
#pragma unroll
  for (int ii = 0; ii < 8; ++ii)
#pragma unroll
    for (int jj = 0; jj < 8; ++jj) {
      int r = ty * 8 + ii, c = tx * 8 + jj;
      Gm[(size_t)(ib * 128 + r) * n + jb * 128 + c] = acc[ii][jj];
      if (ib != jb) Gm[(size_t)(jb * 128 + c) * n + ib * 128 + r] = acc[ii][jj];
    }
  if (ib == jb && tx == ty) {
    float td = 0.0f;
#pragma unroll
    for (int ii = 0; ii < 8; ++ii) td += acc[ii][ii];
    atomicAdd(&accp[2], td);
  }
  float rowp[8];
#pragma unroll
  for (int i = 0; i < 8; ++i) {
    float s = 0.0f;
#pragma unroll
    for (int j = 0; j < 8; ++j) s = fmaf(acc[i][j], sm.aj[tx * 8 + j], s);
    rowp[i] = s;
  }
  float colp[8];
  if (ib != jb) {
#pragma unroll
    for (int j = 0; j < 8; ++j) {
      float s = 0.0f;
#pragma unroll
      for (int i = 0; i < 8; ++i) s = fmaf(acc[i][j], sm.ai[ty * 8 + i], s);
      colp[j] = s;
    }
  }
  __syncthreads();
  float* redA = &sm.As[0][0];  // 128 x 16
  float* redB = &sm.Bs[0][0];
#pragma unroll
  for (int i = 0; i < 8; ++i) redA[(ty * 8 + i) * 16 + tx] = rowp[i];
  if (ib != jb) {
#pragma unroll
    for (int j = 0; j < 8; ++j) redB[(tx * 8 + j) * 16 + ty] = colp[j];
  }
  __syncthreads();
  if (tid < 128) {
    float s = 0.0f;
#pragma unroll
    for (int q = 0; q < 16; ++q) s += redA[tid * 16 + q];
    atomicAdd(&al[ib * 128 + tid], s);
    if (ib != jb) {
      float s2 = 0.0f;
#pragma unroll
      for (int q = 0; q < 16; ++q) s2 += redB[tid * 16 + q];
      atomicAdd(&al[jb * 128 + tid], s2);
    }
  }
}

// reduce: T1 = <G,C>, T2 = alpha^T C alpha (lower-tri, weight 2 off-diag)
// + ticket: the LAST block runs the Adam update inline. (byte-identical to r8)
__global__ __launch_bounds__(256) void k_reduceAD(const float* __restrict__ xc,
                                                  const float* __restrict__ yc,
                                                  float* ws, int n, int tstep) {
  __shared__ SMem sm;
  __shared__ unsigned tkt;
  int job = blockIdx.x, m = blockIdx.y, tid = threadIdx.x;
  const float* xm = xc + (size_t)m * NC * 3;
  const float* Gm = ws + (size_t)m * 1048576;
  const float* al = ws + OFF_ALPHA + (size_t)m * 1024;
  float* accp = ws + OFF_ACC + m * 8;
  float* sT = ws + OFF_SCAL + m * 32;
  int nb = n >> 6;
  int njobs = nb * (nb + 1) / 2;
  float ls = sT[12], os = sT[13];
  float il2 = 1.0f / (ls * ls);
  float c53 = (5.0f / 3.0f) * os / ls;
  int bi, bj; lt_decode(job, bi, bj);
  float w = (bi == bj) ? 1.0f : 2.0f;
  if (tid < 64) {
    int r = bi * 64 + tid;
    sm.xi[tid][0] = xm[r * 3 + 0]; sm.xi[tid][1] = xm[r * 3 + 1]; sm.xi[tid][2] = xm[r * 3 + 2];
    sm.ai[tid] = al[r];
  } else if (tid < 128) {
    int lr = tid - 64; int r = bj * 64 + lr;
    sm.xj[lr][0] = xm[r * 3 + 0]; sm.xj[lr][1] = xm[r * 3 + 1]; sm.xj[lr][2] = xm[r * 3 + 2];
    sm.aj[lr] = al[r];
  }
  __syncthreads();
  float a1 = 0.0f, a2 = 0.0f;
  for (int e = tid; e < 4096; e += 256) {
    int r = e >> 6, c = e & 63;
    float d0 = sm.xi[r][0] - sm.xj[c][0], d1 = sm.xi[r][1] - sm.xj[c][1], d2 = sm.xi[r][2] - sm.xj[c][2];
    float r2 = d0 * d0 + d1 * d1 + d2 * d2;
    float z = fmaxf(r2 * il2, 1e-12f);
    float dd = sqrtf(z);
    float Cv = c53 * z * (1.0f + S5 * dd) * __expf(-S5 * dd);
    float g = Gm[(size_t)(bi * 64 + r) * n + bj * 64 + c];
    a1 = fmaf(g, Cv, a1);
    a2 = fmaf(sm.ai[r] * sm.aj[c], Cv, a2);
  }
  a1 *= w; a2 *= w;
  for (int off = 32; off; off >>= 1) { a1 += __shfl_down(a1, off); a2 += __shfl_down(a2, off); }
  int wid = tid >> 6, lane = tid & 63;
  if (lane == 0) { sm.red[wid][0] = a1; sm.red[wid][1] = a2; }
  __syncthreads();
  if (tid == 0) {
    a1 = sm.red[0][0] + sm.red[1][0] + sm.red[2][0] + sm.red[3][0];
    a2 = sm.red[0][1] + sm.red[1][1] + sm.red[2][1] + sm.red[3][1];
    atomicAdd(&accp[0], a1);
    atomicAdd(&accp[1], a2);
  }
  __threadfence();
  if (tid == 0)
    tkt = __hip_atomic_fetch_add((unsigned*)(ws + OFF_CTR) + m, 1u,
                                 __ATOMIC_ACQ_REL, __HIP_MEMORY_SCOPE_AGENT);
  __syncthreads();
  if (tkt != (unsigned)(njobs - 1)) return;
  const float* ym = yc + (size_t)m * NC;
  float cm = sT[15];
  float t4 = 0, t5 = 0, t6 = 0;
  for (int i = tid; i < n; i += 256) {
    float a = al[i];
    t4 = fmaf(a, a, t4); t5 += a; t6 = fmaf(ym[i] - cm, a, t6);
  }
  for (int off = 32; off; off >>= 1) {
    t4 += __shfl_down(t4, off); t5 += __shfl_down(t5, off); t6 += __shfl_down(t6, off);
  }
  __syncthreads();
  if (lane == 0) { sm.red[wid][0] = t4; sm.red[wid][1] = t5; sm.red[wid][2] = t6; }
  __syncthreads();
  if (tid == 0) {
    t4 = sm.red[0][0] + sm.red[1][0] + sm.red[2][0] + sm.red[3][0];
    t5 = sm.red[0][1] + sm.red[1][1] + sm.red[2][1] + sm.red[3][1];
    t6 = sm.red[0][2] + sm.red[1][2] + sm.red[2][2] + sm.red[3][2];
    float T1 = __hip_atomic_fetch_add(&accp[0], 0.0f, __ATOMIC_RELAXED, __HIP_MEMORY_SCOPE_AGENT);
    float T2 = __hip_atomic_fetch_add(&accp[1], 0.0f, __ATOMIC_RELAXED, __HIP_MEMORY_SCOPE_AGENT);
    float t3 = __hip_atomic_fetch_add(&accp[2], 0.0f, __ATOMIC_RELAXED, __HIP_MEMORY_SCOPE_AGENT);
    float noi = sT[14];
    float fn = (float)n;
    float g_ls = 0.5f / fn * (T1 - T2);
    float g_os = 0.5f / (fn * os) * (fn - noi * t3 - t6 + noi * t4);
    float g_no = 0.5f / fn * (t3 - t4);
    float g_c = -t5 / fn;
    float gr[4];
    gr[0] = g_ls * sigmf(sT[0]);
    gr[1] = g_os * sigmf(sT[1]);
    gr[2] = g_no * sigmf(sT[2]);
    gr[3] = g_c;
    float bc1 = 1.0f - powf(0.9f, (float)tstep);
    float bc2 = 1.0f - powf(0.999f, (float)tstep);
#pragma unroll
    for (int i = 0; i < 4; ++i) {
      float mv = 0.9f * sT[4 + i] + 0.1f * gr[i];
      float vv = 0.999f * sT[8 + i] + 0.001f * gr[i] * gr[i];
      sT[4 + i] = mv; sT[8 + i] = vv;
      sT[i] = sT[i] - 0.1f * (mv / bc1) / (sqrtf(vv / bc2) + 1e-8f);
    }
    sT[12] = softplusf(sT[0]);
    sT[13] = softplusf(sT[1]);
    sT[14] = softplusf(sT[2]) + 1e-4f;
    sT[15] = sT[3];
  }
}

// prediction (unchanged from r8)
__global__ __launch_bounds__(256) void k_buildKtc(const float* __restrict__ xt,
                                                  const float* __restrict__ xc, float* ws) {
  __shared__ float xi[64][3], xj[64][3];
  int job = blockIdx.x, m = blockIdx.y, tid = threadIdx.x;
  const float* xtm = xt + (size_t)m * NT * 3;
  const float* xm = xc + (size_t)m * NC * 3;
  float* Kt = ws + OFF_KTC + (size_t)m * NT * NC;
  float* Tm = ws + OFF_T + (size_t)m * 262144;  // S1 at Tm, S2 at Tm+NT
  const float* sT = ws + OFF_SCAL + m * 32;
  float ls = sT[12], os = sT[13];
  float il2 = 1.0f / (ls * ls);
  if (job < 2) {
    int z = job * 256 + tid;
    Tm[z] = 0.0f; Tm[NT + z] = 0.0f;
  }
  int ti = job >> 4, tj = job & 15;
  if (tid < 64) {
    int r = ti * 64 + tid;
    xi[tid][0] = xtm[r * 3 + 0]; xi[tid][1] = xtm[r * 3 + 1]; xi[tid][2] = xtm[r * 3 + 2];
  } else if (tid < 128) {
    int lr = tid - 64; int r = tj * 64 + lr;
    xj[lr][0] = xm[r * 3 + 0]; xj[lr][1] = xm[r * 3 + 1]; xj[lr][2] = xm[r * 3 + 2];
  }
  __syncthreads();
  for (int e = tid; e < 4096; e += 256) {
    int r = e >> 6, c = e & 63;
    float d0 = xi[r][0] - xj[c][0], d1 = xi[r][1] - xj[c][1], d2 = xi[r][2] - xj[c][2];
    float r2 = d0 * d0 + d1 * d1 + d2 * d2;
    float z = fmaxf(r2 * il2, 1e-12f);
    float dd = sqrtf(z);
    float kv = os * (1.0f + S5 * dd + (5.0f / 3.0f) * z) * __expf(-S5 * dd);
    Kt[(size_t)(ti * 64 + r) * NC + tj * 64 + c] = kv;
  }
}

// W-tile = Ktc*G in-register; fused S1 += Ktc.alpha, S2 += Ktc.W (r8)
__global__ __launch_bounds__(256) void k_predW(float* ws) {
  __shared__ SMem sm;
  int job = blockIdx.x, m = blockIdx.y, tid = threadIdx.x;
  int tx = tid & 15, ty = tid >> 4;
  const float* Kt = ws + OFF_KTC + (size_t)m * NT * NC;
  const float* Gm = ws + (size_t)m * 1048576;
  const float* al = ws + OFF_ALPHA + (size_t)m * 1024;
  float* S1 = ws + OFF_T + (size_t)m * 262144;
  float* S2 = S1 + NT;
  int ti = job >> 4, tj = job & 15;
  if (tid < 64) sm.aj[tid] = al[tj * 64 + tid];
  float acc[4][4] = {};
  gemm64<0, 0>(Kt + (size_t)(ti * 64) * NC, NC, Gm + tj * 64, 1024, 0, 1024, acc, sm);
  float s1p[4], s2p[4];
#pragma unroll
  for (int i = 0; i < 4; ++i) {
    float a1 = 0.0f, a2 = 0.0f;
    const float* kr = Kt + (size_t)(ti * 64 + ty * 4 + i) * NC + tj * 64;
#pragma unroll
    for (int j = 0; j < 4; ++j) {
      float kv = kr[tx * 4 + j];
      a1 = fmaf(kv, sm.aj[tx * 4 + j], a1);
      a2 = fmaf(kv, acc[i][j], a2);
    }
    s1p[i] = a1; s2p[i] = a2;
  }
  __syncthreads();
  float* redA = &sm.As[0][0];
  float* redB = &sm.Bs[0][0];
#pragma unroll
  for (int i = 0; i < 4; ++i) {
    redA[(ty * 4 + i) * 16 + tx] = s1p[i];
    redB[(ty * 4 + i) * 16 + tx] = s2p[i];
  }
  __syncthreads();
  if (tid < 64) {
    float a1 = 0.0f, a2 = 0.0f;
#pragma unroll
    for (int q = 0; q < 16; ++q) { a1 += redA[tid * 16 + q]; a2 += redB[tid * 16 + q]; }
    atomicAdd(&S1[ti * 64 + tid], a1);
    atomicAdd(&S2[ti * 64 + tid], a2);
  }
}

__global__ __launch_bounds__(256) void k_final(float* ws, float* out) {
  int m = blockIdx.y, t = blockIdx.x * 256 + threadIdx.x;
  const float* S1 = ws + OFF_T + (size_t)m * 262144;
  const float* S2 = S1 + NT;
  const float* sT = ws + OFF_SCAL + m * 32;
  if (t < NT) {
    out[(size_t)m * NT + t] = sT[15] + S1[t];
    out[(size_t)MM * NT + (size_t)m * NT + t] = sT[13] + sT[14] - S2[t];
  }
}

// ---------------- host: discrete graph pipeline ------------------------------
extern "C" void kernel_launch(void* const* d_in, const int* in_sizes, int n_in,
                              void* d_out, int out_size, void* d_ws, size_t ws_size,
                              hipStream_t stream) {
  const float* xc = (const float*)d_in[0];
  const float* yc = (const float*)d_in[1];
  const float* xt = (const float*)d_in[2];
  float* out = (float*)d_out;
  float* ws = (float*)d_ws;

  k_init<<<dim3(1), dim3(256), 0, stream>>>(ws);

  for (int step = 0; step < 17; ++step) {
    int n = step < 8 ? 512 : 1024;
    int nb = n >> 6, nb128 = n >> 7;
    k_buildK<<<dim3(nb * (nb + 1) / 2, MM), dim3(256), 0, stream>>>(xc, ws, n);
    k_factor128<<<dim3(MM), dim3(256), 0, stream>>>(ws, 0, n);
    for (int k = 0; k <= nb128 - 2; ++k) {
      int t = nb128 - 1 - k;
      k_panel128<<<dim3(t, MM), dim3(256), 0, stream>>>(ws, k, n);
      k_trailF128<<<dim3(t * (t + 1) / 2, MM), dim3(256), 0, stream>>>(ws, k, n);
    }
    for (int s = 128; s < n; s <<= 1) {
      int st = s >> 7, np = n / (2 * s);
      k_trinvT<<<dim3(np * st * st, MM), dim3(256), 0, stream>>>(ws, s, n);
      k_trinvA<<<dim3(np * st * st, MM), dim3(256), 0, stream>>>(ws, s, n);
    }
    k_syrkAT<<<dim3(nb128 * (nb128 + 1) / 2, MM), dim3(256), 0, stream>>>(yc, ws, n);
    if (step < 16) {
      k_reduceAD<<<dim3(nb * (nb + 1) / 2, MM), dim3(256), 0, stream>>>(xc, yc, ws, n, step + 1);
    }
  }

  k_buildKtc<<<dim3(128, MM), dim3(256), 0, stream>>>(xt, xc, ws);
  k_predW<<<dim3(128, MM), dim3(256), 0, stream>>>(ws);
  k_final<<<dim3(2, MM), dim3(256), 0, stream>>>(ws, out);

  (void)in_sizes; (void)n_in; (void)out_size; (void)ws_size;
}